// Round 9
// baseline (2007.615 us; speedup 1.0000x reference)
//
#include <hip/hip_runtime.h>

typedef unsigned short u16;
typedef unsigned int u32;
typedef __attribute__((ext_vector_type(8))) __bf16 bf16x8;
typedef __attribute__((ext_vector_type(4))) float f32x4;
typedef __attribute__((ext_vector_type(2))) float f32x2;

#define B_ 64
#define S_ 256
#define OBS_ 96
#define ACT_ 29
#define D_ 512
#define H_ 8
#define L_ 8
#define FF_ 2048
#define HD_ 64
#define NTOK (B_ * S_)   // 16384
#define QKV3 (3 * D_)    // 1536

// native f32->bf16 (gfx950 v_cvt_pk_bf16_f32, RTNE — 1 inst vs 4-inst integer RTNE)
__device__ __forceinline__ u16 f2bf(float f) {
    __bf16 h = (__bf16)f;
    u16 u; __builtin_memcpy(&u, &h, 2); return u;
}
__device__ __forceinline__ float bf2f(u16 h) {
    return __uint_as_float(((u32)h) << 16);
}
__device__ __forceinline__ u16 f2h(float f) {
    _Float16 h = (_Float16)f;
    u16 u; __builtin_memcpy(&u, &h, 2); return u;
}
__device__ __forceinline__ float h2f(u16 u) {
    _Float16 h; __builtin_memcpy(&h, &u, 2); return (float)h;
}
// 7-inst GELU: x*sigmoid(2z), z = 0.79788456(x+0.044715x^3), exp2/rcp form.
__device__ __forceinline__ float gelu_f(float x) {
    const float k1 = 2.3022121f;    // 2*0.79788456*log2(e)
    const float k2 = 0.10294451f;   // k1*0.044715
    float x2 = x * x;
    float arg = x * __builtin_fmaf(x2, k2, k1);
    float e = exp2f(arg);
    float r = __builtin_amdgcn_rcpf(1.0f + e);
    return __builtin_fmaf(-x, r, x);
}
// packed-pair GELU: vector ops lower to v_pk_* on CDNA; exp2/rcp stay scalar.
__device__ __forceinline__ f32x2 gelu2(f32x2 x) {
    const float k1 = 2.3022121f;
    const float k2 = 0.10294451f;
    f32x2 x2 = x * x;
    f32x2 arg = x * (x2 * k2 + k1);
    f32x2 e;
    e.x = exp2f(arg.x);
    e.y = exp2f(arg.y);
    f32x2 one_e = e + 1.0f;
    f32x2 r;
    r.x = __builtin_amdgcn_rcpf(one_e.x);
    r.y = __builtin_amdgcn_rcpf(one_e.y);
    return x - x * r;
}
// async global->LDS, 16B per lane. LDS dest is wave-uniform base + lane*16.
__device__ __forceinline__ void gld_lds16(const u16* g, u16* l) {
    __builtin_amdgcn_global_load_lds(
        (const __attribute__((address_space(1))) unsigned int*)g,
        (__attribute__((address_space(3))) unsigned int*)l, 16, 0, 0);
}

// ---------------------------------------------------------------------------
// Transpose + downcast: src fp32 [z][K][N] -> dst bf16 [z][N][K] (strided)
// ---------------------------------------------------------------------------
__global__ __launch_bounds__(256) void transpose_bf16_kernel(
    const float* __restrict__ src, u16* __restrict__ dst, int K, int N,
    size_t srcStride, size_t dstStride)
{
    __shared__ float tile[32][33];
    int n0 = blockIdx.x * 32, k0 = blockIdx.y * 32;
    const float* s = src + (size_t)blockIdx.z * srcStride;
    u16* d = dst + (size_t)blockIdx.z * dstStride;
    int tx = threadIdx.x, ty = threadIdx.y;   // block (32,8)
    for (int i = 0; i < 32; i += 8)
        tile[ty + i][tx] = s[(size_t)(k0 + ty + i) * N + n0 + tx];
    __syncthreads();
    for (int i = 0; i < 32; i += 8)
        d[(size_t)(n0 + ty + i) * K + k0 + tx] = f2bf(tile[tx][ty + i]);
}

__global__ __launch_bounds__(256) void concat_bias_kernel(
    const float* __restrict__ bq, const float* __restrict__ bk,
    const float* __restrict__ bv, float* __restrict__ dst)
{
    int i = blockIdx.x * 256 + threadIdx.x;      // over L*1536
    int l = i / QKV3, r = i - l * QKV3;
    float v;
    if (r < D_)            v = bq[l * D_ + r];
    else if (r < 2 * D_)   v = bk[l * D_ + r - D_];
    else                   v = bv[l * D_ + r - 2 * D_];
    dst[i] = v;
}

// ---------------------------------------------------------------------------
// Input projection GEMM (fp32): outp[M][512] = obs[M][96] @ Win[96][512] + b
// ---------------------------------------------------------------------------
__global__ __launch_bounds__(256) void in_gemm_kernel(
    const float* __restrict__ obs, const float* __restrict__ Win,
    const float* __restrict__ b_in, float* __restrict__ outp)
{
    __shared__ float As[OBS_][68];
    __shared__ float Bs[OBS_][68];
    int m0 = blockIdx.y * 64, n0 = blockIdx.x * 64;
    int t = threadIdx.x;
    #pragma unroll
    for (int i = 0; i < 24; i++) {
        int idx = i * 256 + t;
        int m = idx / OBS_, kk = idx - m * OBS_;
        As[kk][m] = obs[(size_t)(m0 + m) * OBS_ + kk];
    }
    #pragma unroll
    for (int i = 0; i < 24; i++) {
        int idx = i * 256 + t;
        int kk = idx >> 6, n = idx & 63;
        Bs[kk][n] = Win[(size_t)kk * D_ + n0 + n];
    }
    __syncthreads();
    int tm = t >> 4, tn = t & 15;
    float acc[4][4] = {};
    for (int kk = 0; kk < OBS_; kk++) {
        float4 a = *(const float4*)&As[kk][tm * 4];
        float4 b = *(const float4*)&Bs[kk][tn * 4];
        const float av[4] = {a.x, a.y, a.z, a.w};
        const float bv[4] = {b.x, b.y, b.z, b.w};
        #pragma unroll
        for (int r = 0; r < 4; r++)
            #pragma unroll
            for (int c = 0; c < 4; c++) acc[r][c] += av[r] * bv[c];
    }
    #pragma unroll
    for (int r = 0; r < 4; r++)
        #pragma unroll
        for (int c = 0; c < 4; c++) {
            int col = n0 + tn * 4 + c;
            outp[(size_t)(m0 + tm * 4 + r) * D_ + col] = acc[r][c] + b_in[col];
        }
}

// ---------------------------------------------------------------------------
// GEMM: C[M][N] = A[M][K] @ BT[N][K] + bias (bf16 in).
// R9: BK=32 TRIPLE-BUFFER with COUNTED vmcnt (T4). The R3/R8 structure's
// limiter is the full vmcnt(0)+lgkmcnt(0) drain inside __syncthreads every
// K-step. Here: raw s_barrier + `s_waitcnt vmcnt(LPT)` — waits ONLY tile
// kt's loads, leaves kt+1's in flight ACROSS the barrier (never 0 until the
// final iter). Stage kt+2 after the barrier into the buffer holding kt-1
// (provably dead: its readers passed this barrier). 3 x 16KB = 48KB LDS
// keeps 3 blocks/CU (R4's 64KB/2-blk mistake avoided). Fragment offsets +
// 4-slot swizzle are R6's refcheck-passed BK=32 code verbatim.
// Falsified (do NOT retry): R4 full-BK dbuf w/ syncthreads; R5 min-waves=5;
// R6 half-K dbuf w/ syncthreads (drained vmcnt -> paid contention, no gain).
// Y-fast 1D grid: y = bx & 127, x = bx >> 7 (same-row blocks co-XCD).
// EPI: 0 = bf16, 1 = bf16+GELU, 2 = fp32 direct, 3 = fp16
// u16 outputs (EPI 0/1/3) go through an LDS-staged coalesced store (16B/lane).
// SPLITK: gridDim.z==2; z=0 -> C(+bias), z=1 -> C2 (no bias), both fp16.
// ---------------------------------------------------------------------------
template <int EPI, int TN, bool SPLITK>
__global__ __launch_bounds__(256, 3) void gemm_bt_kernel(
    const u16* __restrict__ A, const u16* __restrict__ BT,
    const float* __restrict__ bias, void* __restrict__ C,
    void* __restrict__ C2, int M, int N, int K, int kLen)
{
    constexpr int NI = TN / 32;               // acc tiles per wave in N
    constexpr int ACH = 2;                    // A chunks per thread per stage
    constexpr int BCH = TN / 64;              // B chunks per thread per stage
    constexpr int LPT = ACH + BCH;            // vmem insts per stage per wave
    constexpr int ABUF = 128 * 32;            // u16 elems per A buffer
    constexpr int BBUF = TN * 32;             // u16 elems per B buffer
    constexpr int BUF = ABUF + BBUF;
    __shared__ __align__(16) u16 smem[3 * BUF];
    int bx = blockIdx.x;
    int m0 = (bx & 127) * 128, n0 = (bx >> 7) * TN;
    int z = SPLITK ? blockIdx.z : 0;
    int kStart = z * kLen;
    int t = threadIdx.x;
    int lane = t & 63, w = t >> 6;
    int wm = w >> 1, wn = w & 1;
    int l15 = lane & 15, quad = lane >> 4;

    // staging: 4 chunks/row of 8 elems; LDS slot s holds global chunk
    // s ^ sw(r), sw(r) = (r^(r>>2))&3 (2-way max on read — free per m136).
    int offA[ACH], offB[BCH];
    #pragma unroll
    for (int i = 0; i < ACH; i++) {
        int ci = t + i * 256;
        int r = ci >> 2, s = ci & 3, gc = s ^ ((r ^ (r >> 2)) & 3);
        offA[i] = r * K + gc * 8;
    }
    #pragma unroll
    for (int i = 0; i < BCH; i++) {
        int ci = t + i * 256;
        int r = ci >> 2, s = ci & 3, gc = s ^ ((r ^ (r >> 2)) & 3);
        offB[i] = r * K + gc * 8;
    }
    const u16* Ag = A + (size_t)m0 * K + kStart;
    const u16* Bg = BT + (size_t)n0 * K + kStart;

    // fragment offsets (elements) within one 32-col buffer (R6 verbatim)
    int aoff[4], boff[NI];
    #pragma unroll
    for (int mi = 0; mi < 4; mi++) {
        int row = wm * 64 + mi * 16 + l15;
        aoff[mi] = row * 32 + ((quad ^ ((row ^ (row >> 2)) & 3)) * 8);
    }
    #pragma unroll
    for (int ni = 0; ni < NI; ni++) {
        int row = wn * (TN / 2) + ni * 16 + l15;
        boff[ni] = row * 32 + ((quad ^ ((row ^ (row >> 2)) & 3)) * 8);
    }

    f32x4 acc[4][NI];
    f32x4 zero = {0.f, 0.f, 0.f, 0.f};
    #pragma unroll
    for (int mi = 0; mi < 4; mi++)
        #pragma unroll
        for (int ni = 0; ni < NI; ni++) acc[mi][ni] = zero;

    auto stage = [&](int kt) {
        int bf = kt % 3;
        const u16* Ab = Ag + kt * 32;
        const u16* Bb = Bg + kt * 32;
        u16* dA = smem + bf * BUF;
        u16* dB = dA + ABUF;
        #pragma unroll
        for (int i = 0; i < ACH; i++) gld_lds16(Ab + offA[i], dA + (t + i * 256) * 8);
        #pragma unroll
        for (int i = 0; i < BCH; i++) gld_lds16(Bb + offB[i], dB + (t + i * 256) * 8);
    };

    int nk = kLen >> 5;
    stage(0);
    if (nk > 1) stage(1);
    for (int kt = 0; kt < nk; ++kt) {
        // Wait ONLY for tile kt's stage (oldest LPT loads); kt+1's stay in
        // flight across the barrier. Last iter drains fully.
        if (kt + 1 < nk) {
            asm volatile("s_waitcnt vmcnt(%0)" :: "i"(LPT) : "memory");
        } else {
            asm volatile("s_waitcnt vmcnt(0)" ::: "memory");
        }
        __builtin_amdgcn_sched_barrier(0);    // rule #18: pin code after wait
        __builtin_amdgcn_s_barrier();         // raw barrier: NO implicit drain
        if (kt + 2 < nk) stage(kt + 2);       // overwrites kt-1's buffer: its
                                              // readers passed this barrier.
        const u16* As_ = smem + (kt % 3) * BUF;
        const u16* Bs_ = As_ + ABUF;
        bf16x8 a[4], b[NI];
        #pragma unroll
        for (int mi = 0; mi < 4; mi++)
            a[mi] = *(const bf16x8*)&As_[aoff[mi]];
        #pragma unroll
        for (int ni = 0; ni < NI; ni++)
            b[ni] = *(const bf16x8*)&Bs_[boff[ni]];
        #pragma unroll
        for (int mi = 0; mi < 4; mi++)
            #pragma unroll
            for (int ni = 0; ni < NI; ni++)
                acc[mi][ni] = __builtin_amdgcn_mfma_f32_16x16x32_bf16(
                    a[mi], b[ni], acc[mi][ni], 0, 0, 0);
    }
    // loop exit: last iter waited vmcnt(0); no stages after -> none in flight.

    bool partial = SPLITK && (z == 1);
    if (EPI == 2) {
        // direct fp32 stores (64B row segments — sector-sized, no ghost)
        #pragma unroll
        for (int ni = 0; ni < NI; ni++) {
            int col = n0 + wn * (TN / 2) + ni * 16 + l15;
            float bv = partial ? 0.f : bias[col];
            #pragma unroll
            for (int mi = 0; mi < 4; mi++) {
                int rbase = m0 + wm * 64 + mi * 16 + quad * 4;
                f32x4 v = acc[mi][ni];
                #pragma unroll
                for (int r = 0; r < 4; r++)
                    ((float*)C)[(size_t)(rbase + r) * N + col] = v[r] + bv;
            }
        }
    } else {
        // LDS-staged coalesced u16 store; pk-fp32 bias+GELU, native cvt.
        // Ct = 128*TN u16 <= 3*BUF for TN in {64,128}.
        __syncthreads();
        u16* Ct = smem;
        #pragma unroll
        for (int ni = 0; ni < NI; ni++) {
            int colt = wn * (TN / 2) + ni * 16 + l15;      // tile-local col
            float bv = partial ? 0.f : bias[n0 + colt];
            #pragma unroll
            for (int mi = 0; mi < 4; mi++) {
                int rbase = wm * 64 + mi * 16 + quad * 4;  // tile-local row
                f32x4 v = acc[mi][ni];
                f32x2 y01 = {v[0], v[1]};
                f32x2 y23 = {v[2], v[3]};
                y01 = y01 + bv;
                y23 = y23 + bv;
                if (EPI == 1) { y01 = gelu2(y01); y23 = gelu2(y23); }
                const float ys[4] = {y01.x, y01.y, y23.x, y23.y};
                #pragma unroll
                for (int r = 0; r < 4; r++) {
                    u16 hv = (EPI == 3) ? f2h(ys[r]) : f2bf(ys[r]);
                    int row = rbase + r;
                    int cc = colt >> 3;
                    Ct[row * TN + (((cc ^ (row & 7)) * 8) | (colt & 7))] = hv;
                }
            }
        }
        __syncthreads();
        u16* dst = partial ? (u16*)C2 : (u16*)C;
        constexpr int CPR = TN / 8;
        #pragma unroll
        for (int i = 0; i < TN / 16; i++) {
            int ch = t + i * 256;
            int row = ch / CPR, cc = ch % CPR;
            uint4 vv = *(const uint4*)&Ct[row * TN + ((cc ^ (row & 7)) * 8)];
            *(uint4*)(dst + (size_t)(m0 + row) * N + n0 + cc * 8) = vv;
        }
    }
}

// ---------------------------------------------------------------------------
// Attention on fused qkv [NTOK][1536]. Block = (b,h,64 q rows). LDS swizzled.
// R8 version (best): early V-loads into registers (T14) ride the K-staging
// latency; K staging coalesced 8-lanes-per-row (128B segments).
// P stored UNNORMALIZED (exp only); 1/sum folded into accO after PV.
// ---------------------------------------------------------------------------
__global__ __launch_bounds__(256) void attn_kernel(
    const u16* __restrict__ qkv, u16* __restrict__ o)
{
    __shared__ __align__(16) u16 kvs[S_ * HD_];      // 32 KB: K rows, then V^T
    __shared__ __align__(16) u16 P[4 * 16 * S_];     // 32 KB: per-wave probs
    int bx = blockIdx.x;
    int qc = bx & 3;
    int h = (bx >> 2) & 7;
    int b = bx >> 5;
    int t = threadIdx.x;
    int lane = t & 63, w = t >> 6;
    int l15 = lane & 15, quad = lane >> 4;
    size_t rowb = (size_t)b * S_;

    // EARLY V loads: thread t holds V row t (8 uint4 = 32 VGPR); the
    // global latency lands in parallel with K staging below.
    uint4 vreg[8];
    {
        const u16* src = qkv + (rowb + t) * QKV3 + 2 * D_ + h * HD_;
        #pragma unroll
        for (int dj = 0; dj < 8; dj++) vreg[dj] = *(const uint4*)(src + dj * 8);
    }
    // stage K coalesced: lane covers chunk (t&7) of rows (t>>3)+32j —
    // 8 lanes per row -> 128B contiguous global segments. Same LDS swizzle:
    // row r, chunk c at slot c^(r&7).
    {
        int chunk = t & 7, row0 = t >> 3;
        #pragma unroll
        for (int j = 0; j < 8; j++) {
            int row = row0 + j * 32;
            const u16* src = qkv + (rowb + row) * QKV3 + D_ + h * HD_ + chunk * 8;
            *(uint4*)&kvs[row * HD_ + ((chunk ^ (row & 7)) * 8)] =
                *(const uint4*)src;
        }
    }
    bf16x8 aQ[2];
    {
        int qrow = qc * 64 + w * 16 + l15;
        const u16* src = qkv + (rowb + qrow) * QKV3 + h * HD_ + quad * 8;
        aQ[0] = *(const bf16x8*)(src);
        aQ[1] = *(const bf16x8*)(src + 32);
    }
    __syncthreads();

    // phase 1: S = Q K^T  (wave computes 16 x 256)
    f32x4 sc[16];
    #pragma unroll
    for (int nc = 0; nc < 16; nc++) {
        f32x4 acc = {0.f, 0.f, 0.f, 0.f};
        int row = nc * 16 + l15;
        int s0 = quad ^ (row & 7);
        bf16x8 b0 = *(const bf16x8*)&kvs[row * HD_ + s0 * 8];
        bf16x8 b1 = *(const bf16x8*)&kvs[row * HD_ + (s0 ^ 4) * 8];
        acc = __builtin_amdgcn_mfma_f32_16x16x32_bf16(aQ[0], b0, acc, 0, 0, 0);
        acc = __builtin_amdgcn_mfma_f32_16x16x32_bf16(aQ[1], b1, acc, 0, 0, 0);
        sc[nc] = acc;
    }
    const float scale = 0.125f;  // 1/sqrt(64)
    float rmax[4], rinv[4];
    #pragma unroll
    for (int r = 0; r < 4; r++) {
        float mx = -1e30f;
        #pragma unroll
        for (int nc = 0; nc < 16; nc++) mx = fmaxf(mx, sc[nc][r]);
        for (int off = 1; off < 16; off <<= 1) mx = fmaxf(mx, __shfl_xor(mx, off));
        rmax[r] = mx * scale;
    }
    #pragma unroll
    for (int r = 0; r < 4; r++) {
        float sum = 0.f;
        #pragma unroll
        for (int nc = 0; nc < 16; nc++) {
            float p = __expf(sc[nc][r] * scale - rmax[r]);
            sc[nc][r] = p;
            sum += p;
        }
        for (int off = 1; off < 16; off <<= 1) sum += __shfl_xor(sum, off);
        rinv[r] = 1.0f / sum;
    }
    // P store (bf16, unnormalized), chunk-swizzled per row
    #pragma unroll
    for (int nc = 0; nc < 16; nc++)
        #pragma unroll
        for (int r = 0; r < 4; r++) {
            int prow = quad * 4 + r;
            int col = nc * 16 + l15;
            int slot = (col >> 3) ^ (prow & 7);
            P[w * 4096 + prow * 256 + slot * 8 + (col & 7)] = f2bf(sc[nc][r]);
        }
    __syncthreads();  // all waves done reading K + writing P

    // scatter V^T[64 d][256 s] from registers, chunk-swizzled:
    // row d, chunk c at slot c^(d&7)
    {
        int chunkc = t >> 3, bytec = t & 7;
        #pragma unroll
        for (int dj = 0; dj < 8; dj++) {
            const u16* xs = (const u16*)&vreg[dj];
            #pragma unroll
            for (int i = 0; i < 8; i++) {
                int vrow = dj * 8 + i;
                kvs[vrow * 256 + ((chunkc ^ (vrow & 7)) * 8) + bytec] = xs[i];
            }
        }
    }
    __syncthreads();

    // phase 2: O = P @ V   (wave: 16 x 64)
    f32x4 accO[4];
    f32x4 zero = {0.f, 0.f, 0.f, 0.f};
    #pragma unroll
    for (int nt = 0; nt < 4; nt++) accO[nt] = zero;
    for (int ks = 0; ks < 8; ks++) {
        int ch = ks * 4 + quad;
        bf16x8 aP = *(const bf16x8*)&P[w * 4096 + l15 * 256 + ((ch ^ (l15 & 7)) * 8)];
        #pragma unroll
        for (int nt = 0; nt < 4; nt++) {
            int vrow = nt * 16 + l15;
            bf16x8 bV = *(const bf16x8*)&kvs[vrow * 256 + ((ch ^ (vrow & 7)) * 8)];
            accO[nt] = __builtin_amdgcn_mfma_f32_16x16x32_bf16(aP, bV, accO[nt], 0, 0, 0);
        }
    }
    // O through LDS (reuse P) -> coalesced 16B stores, 128B row segments
    __syncthreads();
    u16* Ot = P;     // 64 x 64 u16
    #pragma unroll
    for (int nt = 0; nt < 4; nt++)
        #pragma unroll
        for (int r = 0; r < 4; r++) {
            int row = w * 16 + quad * 4 + r;
            int col = nt * 16 + l15;
            int cc = col >> 3;
            Ot[row * 64 + (((cc ^ (row & 7)) * 8) | (col & 7))] =
                f2bf(accO[nt][r] * rinv[r]);
        }
    __syncthreads();
    #pragma unroll
    for (int i = 0; i < 2; i++) {
        int ch = t + i * 256;
        int row = ch >> 3, cc = ch & 7;
        uint4 vv = *(const uint4*)&Ot[row * 64 + ((cc ^ (row & 7)) * 8)];
        *(uint4*)(o + (rowb + qc * 64 + row) * D_ + h * HD_ + cc * 8) = vv;
    }
}

// ---------------------------------------------------------------------------
// LayerNorm: out = LN(in [+ in2] [+ res]) * g + b, optional GELU / PE.
// Vectorized: 4 elems/thread (8-16 B/lane), T = WIDTH/4 threads per row,
// R = 256/T rows per block. INK: 0 = fp32 inputs, 1 = fp16 inputs.
// ---------------------------------------------------------------------------
template <int WIDTH, int INK, bool RES, bool GELU, bool PE, bool SUM2>
__global__ __launch_bounds__(256) void ln_kernel(
    const void* __restrict__ in, const void* __restrict__ in2,
    const u16* __restrict__ res,
    const float* __restrict__ g, const float* __restrict__ b,
    u16* __restrict__ out)
{
    constexpr int T = WIDTH / 4;     // threads per row (32 / 64 / 128)
    constexpr int R = 256 / T;       // rows per block
    __shared__ float rs[R][2], rq[R][2];   // only used when T == 128
    int t = threadIdx.x;
    int r = t / T, j = t % T;
    int row = blockIdx.x * R + r;
    size_t base = (size_t)row * WIDTH + j * 4;
    float v[4];
    if (INK == 0) {
        float4 x = *(const float4*)((const float*)in + base);
        v[0] = x.x; v[1] = x.y; v[2] = x.z; v[3] = x.w;
    } else {
        uint2 x = *(const uint2*)((const u16*)in + base);
        const u16* xs = (const u16*)&x;
        #pragma unroll
        for (int i = 0; i < 4; i++) v[i] = h2f(xs[i]);
    }
    if (SUM2) {
        if (INK == 0) {
            float4 x = *(const float4*)((const float*)in2 + base);
            v[0] += x.x; v[1] += x.y; v[2] += x.z; v[3] += x.w;
        } else {
            uint2 x = *(const uint2*)((const u16*)in2 + base);
            const u16* xs = (const u16*)&x;
            #pragma unroll
            for (int i = 0; i < 4; i++) v[i] += h2f(xs[i]);
        }
    }
    if (RES) {
        uint2 x = *(const uint2*)(res + base);
        const u16* xs = (const u16*)&x;
        #pragma unroll
        for (int i = 0; i < 4; i++) v[i] += bf2f(xs[i]);
    }
    float sm = v[0] + v[1] + v[2] + v[3];
    float sq = v[0] * v[0] + v[1] * v[1] + v[2] * v[2] + v[3] * v[3];
    if constexpr (T >= 64) {
        #pragma unroll
        for (int off = 32; off; off >>= 1) {
            sm += __shfl_xor(sm, off);
            sq += __shfl_xor(sq, off);
        }
    } else {  // T == 32: two rows per wave, confine shuffles to 32 lanes
        #pragma unroll
        for (int off = 16; off; off >>= 1) {
            sm += __shfl_xor(sm, off, 32);
            sq += __shfl_xor(sq, off, 32);
        }
    }
    if constexpr (T == 128) {
        if ((t & 63) == 0) { rs[r][(t >> 6) & 1] = sm; rq[r][(t >> 6) & 1] = sq; }
        __syncthreads();
        sm = rs[r][0] + rs[r][1];
        sq = rq[r][0] + rq[r][1];
    }
    float mean = sm / (float)WIDTH;
    float var = sq / (float)WIDTH - mean * mean;
    float rstd = rsqrtf(var + 1e-5f);
    float4 gv = *(const float4*)(g + j * 4);
    float4 bv = *(const float4*)(b + j * 4);
    const float gs[4] = {gv.x, gv.y, gv.z, gv.w};
    const float bs[4] = {bv.x, bv.y, bv.z, bv.w};
    u16 o4[4];
    #pragma unroll
    for (int i = 0; i < 4; i++) {
        float y = (v[i] - mean) * rstd * gs[i] + bs[i];
        if (GELU) y = gelu_f(y);
        if (PE) {
            const float c = -9.210340371976184f / (float)D_;  // -ln(10000)/D
            int s = row & (S_ - 1);
            int col = j * 4 + i;
            int i2 = col >> 1;
            float ang = (float)s * __expf((float)(2 * i2) * c);
            y += (col & 1) ? __cosf(ang) : __sinf(ang);
        }
        o4[i] = f2bf(y);
    }
    uint2 ov;
    ov.x = (u32)o4[0] | ((u32)o4[1] << 16);
    ov.y = (u32)o4[2] | ((u32)o4[3] << 16);
    *(uint2*)(out + base) = ov;
}

// ---------------------------------------------------------------------------
// Head: out = tanh(y2 @ Wp3 + bp3) * scale + bias. 8 rows x 32 cols per block.
// ---------------------------------------------------------------------------
__global__ __launch_bounds__(256) void head_kernel(
    const u16* __restrict__ y2, const float* __restrict__ W,
    const float* __restrict__ bias, const float* __restrict__ scl,
    const float* __restrict__ bs, float* __restrict__ out)
{
    __shared__ float Ws[128 * ACT_];
    __shared__ u16 Ys[8 * 128];
    int t = threadIdx.x;
    for (int i = t; i < 128 * ACT_; i += 256) Ws[i] = W[i];
    int r0 = blockIdx.x * 8;
    for (int i = t; i < 8 * 128; i += 256) Ys[i] = y2[(size_t)r0 * 128 + i];
    __syncthreads();
    int lr = t >> 5, c = t & 31;
    if (c < ACT_) {
        float acc = bias[c];
        for (int kk = 0; kk < 128; kk++)
            acc += bf2f(Ys[lr * 128 + kk]) * Ws[kk * ACT_ + c];
        float y = tanhf(acc);
        out[(size_t)(r0 + lr) * ACT_ + c] = y * scl[c] + bs[c];
    }
}

// ---------------------------------------------------------------------------
extern "C" void kernel_launch(void* const* d_in, const int* in_sizes, int n_in,
                              void* d_out, int out_size, void* d_ws, size_t ws_size,
                              hipStream_t stream)
{
    const float* obs   = (const float*)d_in[0];
    const float* W_in  = (const float*)d_in[1];
    const float* b_in  = (const float*)d_in[2];
    const float* g_in  = (const float*)d_in[3];
    const float* be_in = (const float*)d_in[4];
    const float* Wq  = (const float*)d_in[5];
    const float* bq  = (const float*)d_in[6];
    const float* Wk  = (const float*)d_in[7];
    const float* bk  = (const float*)d_in[8];
    const float* Wv  = (const float*)d_in[9];
    const float* bv  = (const float*)d_in[10];
    const float* Wo  = (const float*)d_in[11];
    const float* bo  = (const float*)d_in[12];
    const float* g1  = (const float*)d_in[13];
    const float* be1 = (const float*)d_in[14];
    const float* W1  = (const float*)d_in[15];
    const float* b1  = (const float*)d_in[16];
    const float* W2  = (const float*)d_in[17];
    const float* b2  = (const float*)d_in[18];
    const float* g2  = (const float*)d_in[19];
    const float* be2 = (const float*)d_in[20];
    const float* Wp1  = (const float*)d_in[21];
    const float* bp1  = (const float*)d_in[22];
    const float* gp1  = (const float*)d_in[23];
    const float* bep1 = (const float*)d_in[24];
    const float* Wp2  = (const float*)d_in[25];
    const float* bp2  = (const float*)d_in[26];
    const float* gp2  = (const float*)d_in[27];
    const float* bep2 = (const float*)d_in[28];
    const float* Wp3  = (const float*)d_in[29];
    const float* bp3  = (const float*)d_in[30];
    const float* ascl = (const float*)d_in[31];
    const float* abias = (const float*)d_in[32];

    char* ws = (char*)d_ws;
    size_t off = 0;
    auto alloc = [&](size_t bytes) {
        void* p = ws + off;
        off += (bytes + 255) & ~(size_t)255;
        return p;
    };
    u16* WQKVT = (u16*)alloc((size_t)L_ * QKV3 * D_ * 2);     // 12.6 MB
    u16* WOT   = (u16*)alloc((size_t)L_ * D_ * D_ * 2);       // 4 MB
    u16* W1T   = (u16*)alloc((size_t)L_ * D_ * FF_ * 2);      // 16 MB
    u16* W2T   = (u16*)alloc((size_t)L_ * FF_ * D_ * 2);      // 16 MB
    u16* WP1T  = (u16*)alloc((size_t)D_ * (D_ / 2) * 2);
    u16* WP2T  = (u16*)alloc((size_t)(D_ / 2) * (D_ / 4) * 2);
    float* bqkv = (float*)alloc((size_t)L_ * QKV3 * 4);
    u16* x_bf = (u16*)alloc((size_t)NTOK * D_ * 2);           // 16 MB
    float* tmp = (float*)alloc((size_t)NTOK * D_ * 4);        // 32 MB (f32 or f16 use)
    char* regionA = (char*)alloc((size_t)NTOK * FF_ * 2);     // 64 MB
    size_t base_need = off;
    char* tmp2 = ws + base_need;                              // +16 MB if fits
    bool split = (ws_size >= base_need + (size_t)NTOK * D_ * 2);
    (void)in_sizes; (void)n_in; (void)out_size;

    u16* qkvbuf = (u16*)(regionA);                            // 48 MB
    u16* obuf = (u16*)(regionA + (size_t)NTOK * QKV3 * 2);    // 16 MB
    u16* hbuf = (u16*)(regionA);                              // 64 MB (aliases)
    // head-phase aliases (regionA free then)
    u16* y1_bf = (u16*)(regionA);                             // 8 MB
    u16* y2_bf = (u16*)(regionA + (32u << 20));               // 4 MB

    dim3 tb(32, 8);
    size_t DD = (size_t)D_ * D_;
    transpose_bf16_kernel<<<dim3(16, 16, L_), tb, 0, stream>>>(
        Wq, WQKVT, D_, D_, DD, (size_t)QKV3 * D_);
    transpose_bf16_kernel<<<dim3(16, 16, L_), tb, 0, stream>>>(
        Wk, WQKVT + DD, D_, D_, DD, (size_t)QKV3 * D_);
    transpose_bf16_kernel<<<dim3(16, 16, L_), tb, 0, stream>>>(
        Wv, WQKVT + 2 * DD, D_, D_, DD, (size_t)QKV3 * D_);
    transpose_bf16_kernel<<<dim3(16, 16, L_), tb, 0, stream>>>(
        Wo, WOT, D_, D_, DD, DD);
    transpose_bf16_kernel<<<dim3(64, 16, L_), tb, 0, stream>>>(
        W1, W1T, D_, FF_, (size_t)D_ * FF_, (size_t)D_ * FF_);
    transpose_bf16_kernel<<<dim3(16, 64, L_), tb, 0, stream>>>(
        W2, W2T, FF_, D_, (size_t)D_ * FF_, (size_t)D_ * FF_);
    transpose_bf16_kernel<<<dim3(8, 16, 1), tb, 0, stream>>>(
        Wp1, WP1T, D_, D_ / 2, 0, 0);
    transpose_bf16_kernel<<<dim3(4, 8, 1), tb, 0, stream>>>(
        Wp2, WP2T, D_ / 2, D_ / 4, 0, 0);
    concat_bias_kernel<<<L_ * QKV3 / 256, 256, 0, stream>>>(bq, bk, bv, bqkv);

    in_gemm_kernel<<<dim3(D_ / 64, NTOK / 64), 256, 0, stream>>>(
        obs, W_in, b_in, tmp);
    ln_kernel<D_, 0, false, true, true, false><<<NTOK / 2, 256, 0, stream>>>(
        tmp, nullptr, nullptr, g_in, be_in, x_bf);

    const int MG = NTOK / 128;  // 128 M-blocks; grid = 128 * NX (y-fast)
    for (int l = 0; l < L_; l++) {
        const u16* wqkvt = WQKVT + (size_t)l * QKV3 * D_;
        const u16* wot = WOT + (size_t)l * DD;
        const u16* w1t = W1T + (size_t)l * D_ * FF_;
        const u16* w2t = W2T + (size_t)l * FF_ * D_;

        gemm_bt_kernel<0, 128, false><<<MG * (QKV3 / 128), 256, 0, stream>>>(
            x_bf, wqkvt, bqkv + l * QKV3, qkvbuf, nullptr, NTOK, QKV3, D_, D_);
        attn_kernel<<<B_ * H_ * (S_ / 64), 256, 0, stream>>>(qkvbuf, obuf);
        if (split) {
            gemm_bt_kernel<3, 128, true><<<dim3(MG * 4, 1, 2), 256, 0, stream>>>(
                obuf, wot, bo + l * D_, tmp, tmp2, NTOK, D_, D_, D_ / 2);
            ln_kernel<D_, 1, true, false, false, true><<<NTOK / 2, 256, 0, stream>>>(
                tmp, tmp2, x_bf, g1 + l * D_, be1 + l * D_, x_bf);
        } else {
            gemm_bt_kernel<2, 128, false><<<MG * 4, 256, 0, stream>>>(
                obuf, wot, bo + l * D_, tmp, nullptr, NTOK, D_, D_, D_);
            ln_kernel<D_, 0, true, false, false, false><<<NTOK / 2, 256, 0, stream>>>(
                tmp, nullptr, x_bf, g1 + l * D_, be1 + l * D_, x_bf);
        }
        gemm_bt_kernel<1, 128, false><<<MG * (FF_ / 128), 256, 0, stream>>>(
            x_bf, w1t, b1 + l * FF_, hbuf, nullptr, NTOK, FF_, D_, D_);
        if (split) {
            gemm_bt_kernel<3, 128, true><<<dim3(MG * 4, 1, 2), 256, 0, stream>>>(
                hbuf, w2t, b2 + l * D_, tmp, tmp2, NTOK, D_, FF_, FF_ / 2);
            ln_kernel<D_, 1, true, false, false, true><<<NTOK / 2, 256, 0, stream>>>(
                tmp, tmp2, x_bf, g2 + l * D_, be2 + l * D_, x_bf);
        } else {
            gemm_bt_kernel<2, 128, false><<<MG * 4, 256, 0, stream>>>(
                hbuf, w2t, b2 + l * D_, tmp, nullptr, NTOK, D_, FF_, FF_);
            ln_kernel<D_, 0, true, false, false, false><<<NTOK / 2, 256, 0, stream>>>(
                tmp, nullptr, x_bf, g2 + l * D_, be2 + l * D_, x_bf);
        }
    }

    // policy head
    if (split) {
        gemm_bt_kernel<3, 64, true><<<dim3(MG * 4, 1, 2), 256, 0, stream>>>(
            x_bf, WP1T, bp1, tmp, tmp2, NTOK, D_ / 2, D_, D_ / 2);
        ln_kernel<D_ / 2, 1, false, true, false, true><<<NTOK / 4, 256, 0, stream>>>(
            tmp, tmp2, nullptr, gp1, bep1, y1_bf);
        gemm_bt_kernel<3, 64, true><<<dim3(MG * 2, 1, 2), 256, 0, stream>>>(
            y1_bf, WP2T, bp2, tmp, tmp2, NTOK, D_ / 4, D_ / 2, D_ / 4);
        ln_kernel<D_ / 4, 1, false, true, false, true><<<NTOK / 8, 256, 0, stream>>>(
            tmp, tmp2, nullptr, gp2, bep2, y2_bf);
    } else {
        gemm_bt_kernel<2, 64, false><<<MG * 4, 256, 0, stream>>>(
            x_bf, WP1T, bp1, tmp, nullptr, NTOK, D_ / 2, D_, D_);
        ln_kernel<D_ / 2, 0, false, true, false, false><<<NTOK / 4, 256, 0, stream>>>(
            tmp, nullptr, nullptr, gp1, bep1, y1_bf);
        gemm_bt_kernel<2, 64, false><<<MG * 2, 256, 0, stream>>>(
            y1_bf, WP2T, bp2, tmp, nullptr, NTOK, D_ / 4, D_ / 2, D_ / 2);
        ln_kernel<D_ / 4, 0, false, true, false, false><<<NTOK / 8, 256, 0, stream>>>(
            tmp, nullptr, nullptr, gp2, bep2, y2_bf);
    }
    head_kernel<<<NTOK / 8, 256, 0, stream>>>(
        y2_bf, Wp3, bp3, ascl, abias, (float*)d_out);
}

// Round 10
// 1806.043 us; speedup vs baseline: 1.1116x; 1.1116x over previous
//
#include <hip/hip_runtime.h>

typedef unsigned short u16;
typedef unsigned int u32;
typedef __attribute__((ext_vector_type(8))) __bf16 bf16x8;
typedef __attribute__((ext_vector_type(4))) float f32x4;
typedef __attribute__((ext_vector_type(2))) float f32x2;

#define B_ 64
#define S_ 256
#define OBS_ 96
#define ACT_ 29
#define D_ 512
#define H_ 8
#define L_ 8
#define FF_ 2048
#define HD_ 64
#define NTOK (B_ * S_)   // 16384
#define QKV3 (3 * D_)    // 1536

// native f32->bf16 (gfx950 v_cvt_pk_bf16_f32, RTNE — 1 inst vs 4-inst integer RTNE)
__device__ __forceinline__ u16 f2bf(float f) {
    __bf16 h = (__bf16)f;
    u16 u; __builtin_memcpy(&u, &h, 2); return u;
}
__device__ __forceinline__ float bf2f(u16 h) {
    return __uint_as_float(((u32)h) << 16);
}
__device__ __forceinline__ u16 f2h(float f) {
    _Float16 h = (_Float16)f;
    u16 u; __builtin_memcpy(&u, &h, 2); return u;
}
__device__ __forceinline__ float h2f(u16 u) {
    _Float16 h; __builtin_memcpy(&h, &u, 2); return (float)h;
}
// 7-inst GELU: x*sigmoid(2z), z = 0.79788456(x+0.044715x^3), exp2/rcp form.
__device__ __forceinline__ float gelu_f(float x) {
    const float k1 = 2.3022121f;    // 2*0.79788456*log2(e)
    const float k2 = 0.10294451f;   // k1*0.044715
    float x2 = x * x;
    float arg = x * __builtin_fmaf(x2, k2, k1);
    float e = exp2f(arg);
    float r = __builtin_amdgcn_rcpf(1.0f + e);
    return __builtin_fmaf(-x, r, x);
}
// packed-pair GELU: vector ops lower to v_pk_* on CDNA; exp2/rcp stay scalar.
__device__ __forceinline__ f32x2 gelu2(f32x2 x) {
    const float k1 = 2.3022121f;
    const float k2 = 0.10294451f;
    f32x2 x2 = x * x;
    f32x2 arg = x * (x2 * k2 + k1);
    f32x2 e;
    e.x = exp2f(arg.x);
    e.y = exp2f(arg.y);
    f32x2 one_e = e + 1.0f;
    f32x2 r;
    r.x = __builtin_amdgcn_rcpf(one_e.x);
    r.y = __builtin_amdgcn_rcpf(one_e.y);
    return x - x * r;
}
// async global->LDS, 16B per lane. LDS dest is wave-uniform base + lane*16.
__device__ __forceinline__ void gld_lds16(const u16* g, u16* l) {
    __builtin_amdgcn_global_load_lds(
        (const __attribute__((address_space(1))) unsigned int*)g,
        (__attribute__((address_space(3))) unsigned int*)l, 16, 0, 0);
}

// ---------------------------------------------------------------------------
// Transpose + downcast: src fp32 [z][K][N] -> dst bf16 [z][N][K] (strided)
// ---------------------------------------------------------------------------
__global__ __launch_bounds__(256) void transpose_bf16_kernel(
    const float* __restrict__ src, u16* __restrict__ dst, int K, int N,
    size_t srcStride, size_t dstStride)
{
    __shared__ float tile[32][33];
    int n0 = blockIdx.x * 32, k0 = blockIdx.y * 32;
    const float* s = src + (size_t)blockIdx.z * srcStride;
    u16* d = dst + (size_t)blockIdx.z * dstStride;
    int tx = threadIdx.x, ty = threadIdx.y;   // block (32,8)
    for (int i = 0; i < 32; i += 8)
        tile[ty + i][tx] = s[(size_t)(k0 + ty + i) * N + n0 + tx];
    __syncthreads();
    for (int i = 0; i < 32; i += 8)
        d[(size_t)(n0 + ty + i) * K + k0 + tx] = f2bf(tile[tx][ty + i]);
}

__global__ __launch_bounds__(256) void concat_bias_kernel(
    const float* __restrict__ bq, const float* __restrict__ bk,
    const float* __restrict__ bv, float* __restrict__ dst)
{
    int i = blockIdx.x * 256 + threadIdx.x;      // over L*1536
    int l = i / QKV3, r = i - l * QKV3;
    float v;
    if (r < D_)            v = bq[l * D_ + r];
    else if (r < 2 * D_)   v = bk[l * D_ + r - D_];
    else                   v = bv[l * D_ + r - 2 * D_];
    dst[i] = v;
}

// ---------------------------------------------------------------------------
// Input projection GEMM (fp32): outp[M][512] = obs[M][96] @ Win[96][512] + b
// ---------------------------------------------------------------------------
__global__ __launch_bounds__(256) void in_gemm_kernel(
    const float* __restrict__ obs, const float* __restrict__ Win,
    const float* __restrict__ b_in, float* __restrict__ outp)
{
    __shared__ float As[OBS_][68];
    __shared__ float Bs[OBS_][68];
    int m0 = blockIdx.y * 64, n0 = blockIdx.x * 64;
    int t = threadIdx.x;
    #pragma unroll
    for (int i = 0; i < 24; i++) {
        int idx = i * 256 + t;
        int m = idx / OBS_, kk = idx - m * OBS_;
        As[kk][m] = obs[(size_t)(m0 + m) * OBS_ + kk];
    }
    #pragma unroll
    for (int i = 0; i < 24; i++) {
        int idx = i * 256 + t;
        int kk = idx >> 6, n = idx & 63;
        Bs[kk][n] = Win[(size_t)kk * D_ + n0 + n];
    }
    __syncthreads();
    int tm = t >> 4, tn = t & 15;
    float acc[4][4] = {};
    for (int kk = 0; kk < OBS_; kk++) {
        float4 a = *(const float4*)&As[kk][tm * 4];
        float4 b = *(const float4*)&Bs[kk][tn * 4];
        const float av[4] = {a.x, a.y, a.z, a.w};
        const float bv[4] = {b.x, b.y, b.z, b.w};
        #pragma unroll
        for (int r = 0; r < 4; r++)
            #pragma unroll
            for (int c = 0; c < 4; c++) acc[r][c] += av[r] * bv[c];
    }
    #pragma unroll
    for (int r = 0; r < 4; r++)
        #pragma unroll
        for (int c = 0; c < 4; c++) {
            int col = n0 + tn * 4 + c;
            outp[(size_t)(m0 + tm * 4 + r) * D_ + col] = acc[r][c] + b_in[col];
        }
}

// ---------------------------------------------------------------------------
// GEMM: C[M][N] = A[M][K] @ BT[N][K] + bias (bf16 in, LDS chunk-swizzled)
// BK=64, single-buffered — R3/R8 config, proven 52.7us FF1, 0 conflicts.
// Structure-experiment family CLOSED (4 falsifications, consistent mechanism):
//   R4 full-BK dbuf + syncthreads: 64KB LDS -> 2 blk/CU, drain retained.
//   R5 min-waves=5: VGPR-bucket scratch spill (FETCH 33->233MB).
//   R6 half-K dbuf + syncthreads: DMA-write vs ds_read LDS port contention
//      (4.2M bank conflicts) with no pipelining gain (drain retained).
//   R9 BK=32 triple-buffer + counted vmcnt + raw s_barrier: wait discipline
//      correct, SAME 4.2M contention -> pipelining on this tile is bounded
//      by the LDS port, not the wait. Drain-then-compute keeps the port
//      conflict-free; 3-block TLP covers the drain. Do NOT re-pipeline this
//      tile; the documented escape is the exact m201 8-phase 256^2 template.
// Y-fast 1D grid: y = bx & 127, x = bx >> 7 (same-row blocks co-XCD).
// EPI: 0 = bf16, 1 = bf16+GELU, 2 = fp32 direct, 3 = fp16
// u16 outputs (EPI 0/1/3) go through an LDS-staged coalesced store (16B/lane).
// SPLITK: gridDim.z==2; z=0 -> C(+bias), z=1 -> C2 (no bias), both fp16.
// ---------------------------------------------------------------------------
template <int EPI, int TN, bool SPLITK>
__global__ __launch_bounds__(256, 3) void gemm_bt_kernel(
    const u16* __restrict__ A, const u16* __restrict__ BT,
    const float* __restrict__ bias, void* __restrict__ C,
    void* __restrict__ C2, int M, int N, int K, int kLen)
{
    constexpr int NI = TN / 32;               // acc tiles per wave in N
    constexpr int NB = TN / 32;               // B staging chunks per thread
    __shared__ __align__(16) u16 smem[128 * 64 + TN * 64];
    u16* As = smem;
    u16* Bs = smem + 128 * 64;
    int bx = blockIdx.x;
    int m0 = (bx & 127) * 128, n0 = (bx >> 7) * TN;
    int z = SPLITK ? blockIdx.z : 0;
    int kStart = z * kLen;
    int t = threadIdx.x;
    int lane = t & 63, w = t >> 6;
    int wm = w >> 1, wn = w & 1;
    int l15 = lane & 15, quad = lane >> 4;

    // staging geometry: chunk ci -> row r = ci>>3, LDS slot s = ci&7 holds
    // global chunk s^(r&7). Same per-thread offsets serve A and B.
    int offC[4]; u16* lA[4];
    #pragma unroll
    for (int i = 0; i < 4; i++) {
        int ci = t + i * 256;
        int r = ci >> 3, s = ci & 7, gc = s ^ (r & 7);
        offC[i] = r * K + gc * 8;
        lA[i] = &As[ci * 8];
    }
    const u16* Abase = A + (size_t)m0 * K + kStart;
    const u16* Bbase = BT + (size_t)n0 * K + kStart;

    // fragment offsets (elements), per k-half
    int aoff[2][4], boff[2][NI];
    #pragma unroll
    for (int kh = 0; kh < 2; kh++) {
        #pragma unroll
        for (int mi = 0; mi < 4; mi++) {
            int row = wm * 64 + mi * 16 + l15;
            aoff[kh][mi] = row * 64 + (((kh * 4 + quad) ^ (row & 7)) * 8);
        }
        #pragma unroll
        for (int ni = 0; ni < NI; ni++) {
            int row = wn * (TN / 2) + ni * 16 + l15;
            boff[kh][ni] = row * 64 + (((kh * 4 + quad) ^ (row & 7)) * 8);
        }
    }

    f32x4 acc[4][NI];
    f32x4 zero = {0.f, 0.f, 0.f, 0.f};
    #pragma unroll
    for (int mi = 0; mi < 4; mi++)
        #pragma unroll
        for (int ni = 0; ni < NI; ni++) acc[mi][ni] = zero;

    for (int kk = 0; kk < kLen; kk += 64) {
        __syncthreads();
        #pragma unroll
        for (int i = 0; i < 4; i++) gld_lds16(Abase + offC[i], lA[i]);
        #pragma unroll
        for (int i = 0; i < NB; i++) gld_lds16(Bbase + offC[i], lA[i] + 128 * 64);
        Abase += 64; Bbase += 64;
        __syncthreads();
        #pragma unroll
        for (int kh = 0; kh < 2; kh++) {
            bf16x8 a[4], b[NI];
            #pragma unroll
            for (int mi = 0; mi < 4; mi++)
                a[mi] = *(const bf16x8*)&As[aoff[kh][mi]];
            #pragma unroll
            for (int ni = 0; ni < NI; ni++)
                b[ni] = *(const bf16x8*)&Bs[boff[kh][ni]];
            #pragma unroll
            for (int mi = 0; mi < 4; mi++)
                #pragma unroll
                for (int ni = 0; ni < NI; ni++)
                    acc[mi][ni] = __builtin_amdgcn_mfma_f32_16x16x32_bf16(
                        a[mi], b[ni], acc[mi][ni], 0, 0, 0);
        }
    }

    bool partial = SPLITK && (z == 1);
    if (EPI == 2) {
        // direct fp32 stores (64B row segments — sector-sized, no ghost)
        #pragma unroll
        for (int ni = 0; ni < NI; ni++) {
            int col = n0 + wn * (TN / 2) + ni * 16 + l15;
            float bv = partial ? 0.f : bias[col];
            #pragma unroll
            for (int mi = 0; mi < 4; mi++) {
                int rbase = m0 + wm * 64 + mi * 16 + quad * 4;
                f32x4 v = acc[mi][ni];
                #pragma unroll
                for (int r = 0; r < 4; r++)
                    ((float*)C)[(size_t)(rbase + r) * N + col] = v[r] + bv;
            }
        }
    } else {
        // LDS-staged coalesced u16 store; pk-fp32 bias+GELU, native cvt
        __syncthreads();
        u16* Ct = smem;   // 128*TN u16, fits in As(+Bs)
        #pragma unroll
        for (int ni = 0; ni < NI; ni++) {
            int colt = wn * (TN / 2) + ni * 16 + l15;      // tile-local col
            float bv = partial ? 0.f : bias[n0 + colt];
            #pragma unroll
            for (int mi = 0; mi < 4; mi++) {
                int rbase = wm * 64 + mi * 16 + quad * 4;  // tile-local row
                f32x4 v = acc[mi][ni];
                f32x2 y01 = {v[0], v[1]};
                f32x2 y23 = {v[2], v[3]};
                y01 = y01 + bv;
                y23 = y23 + bv;
                if (EPI == 1) { y01 = gelu2(y01); y23 = gelu2(y23); }
                const float ys[4] = {y01.x, y01.y, y23.x, y23.y};
                #pragma unroll
                for (int r = 0; r < 4; r++) {
                    u16 hv = (EPI == 3) ? f2h(ys[r]) : f2bf(ys[r]);
                    int row = rbase + r;
                    int cc = colt >> 3;
                    Ct[row * TN + (((cc ^ (row & 7)) * 8) | (colt & 7))] = hv;
                }
            }
        }
        __syncthreads();
        u16* dst = partial ? (u16*)C2 : (u16*)C;
        constexpr int CPR = TN / 8;
        #pragma unroll
        for (int i = 0; i < TN / 16; i++) {
            int ch = t + i * 256;
            int row = ch / CPR, cc = ch % CPR;
            uint4 vv = *(const uint4*)&Ct[row * TN + ((cc ^ (row & 7)) * 8)];
            *(uint4*)(dst + (size_t)(m0 + row) * N + n0 + cc * 8) = vv;
        }
    }
}

// ---------------------------------------------------------------------------
// Attention on fused qkv [NTOK][1536]. Block = (b,h,64 q rows). LDS swizzled.
// R8 version (session best): early V-loads into registers (T14) ride the
// K-staging latency; K staging coalesced 8-lanes-per-row (128B segments).
// P stored UNNORMALIZED (exp only); 1/sum folded into accO after PV
// (row mapping quad*4+r identical in both phases).
// ---------------------------------------------------------------------------
__global__ __launch_bounds__(256) void attn_kernel(
    const u16* __restrict__ qkv, u16* __restrict__ o)
{
    __shared__ __align__(16) u16 kvs[S_ * HD_];      // 32 KB: K rows, then V^T
    __shared__ __align__(16) u16 P[4 * 16 * S_];     // 32 KB: per-wave probs
    int bx = blockIdx.x;
    int qc = bx & 3;
    int h = (bx >> 2) & 7;
    int b = bx >> 5;
    int t = threadIdx.x;
    int lane = t & 63, w = t >> 6;
    int l15 = lane & 15, quad = lane >> 4;
    size_t rowb = (size_t)b * S_;

    // EARLY V loads: thread t holds V row t (8 uint4 = 32 VGPR); the
    // global latency lands in parallel with K staging below.
    uint4 vreg[8];
    {
        const u16* src = qkv + (rowb + t) * QKV3 + 2 * D_ + h * HD_;
        #pragma unroll
        for (int dj = 0; dj < 8; dj++) vreg[dj] = *(const uint4*)(src + dj * 8);
    }
    // stage K coalesced: lane covers chunk (t&7) of rows (t>>3)+32j —
    // 8 lanes per row -> 128B contiguous global segments. Same LDS swizzle:
    // row r, chunk c at slot c^(r&7).
    {
        int chunk = t & 7, row0 = t >> 3;
        #pragma unroll
        for (int j = 0; j < 8; j++) {
            int row = row0 + j * 32;
            const u16* src = qkv + (rowb + row) * QKV3 + D_ + h * HD_ + chunk * 8;
            *(uint4*)&kvs[row * HD_ + ((chunk ^ (row & 7)) * 8)] =
                *(const uint4*)src;
        }
    }
    bf16x8 aQ[2];
    {
        int qrow = qc * 64 + w * 16 + l15;
        const u16* src = qkv + (rowb + qrow) * QKV3 + h * HD_ + quad * 8;
        aQ[0] = *(const bf16x8*)(src);
        aQ[1] = *(const bf16x8*)(src + 32);
    }
    __syncthreads();

    // phase 1: S = Q K^T  (wave computes 16 x 256)
    f32x4 sc[16];
    #pragma unroll
    for (int nc = 0; nc < 16; nc++) {
        f32x4 acc = {0.f, 0.f, 0.f, 0.f};
        int row = nc * 16 + l15;
        int s0 = quad ^ (row & 7);
        bf16x8 b0 = *(const bf16x8*)&kvs[row * HD_ + s0 * 8];
        bf16x8 b1 = *(const bf16x8*)&kvs[row * HD_ + (s0 ^ 4) * 8];
        acc = __builtin_amdgcn_mfma_f32_16x16x32_bf16(aQ[0], b0, acc, 0, 0, 0);
        acc = __builtin_amdgcn_mfma_f32_16x16x32_bf16(aQ[1], b1, acc, 0, 0, 0);
        sc[nc] = acc;
    }
    const float scale = 0.125f;  // 1/sqrt(64)
    float rmax[4], rinv[4];
    #pragma unroll
    for (int r = 0; r < 4; r++) {
        float mx = -1e30f;
        #pragma unroll
        for (int nc = 0; nc < 16; nc++) mx = fmaxf(mx, sc[nc][r]);
        for (int off = 1; off < 16; off <<= 1) mx = fmaxf(mx, __shfl_xor(mx, off));
        rmax[r] = mx * scale;
    }
    #pragma unroll
    for (int r = 0; r < 4; r++) {
        float sum = 0.f;
        #pragma unroll
        for (int nc = 0; nc < 16; nc++) {
            float p = __expf(sc[nc][r] * scale - rmax[r]);
            sc[nc][r] = p;
            sum += p;
        }
        for (int off = 1; off < 16; off <<= 1) sum += __shfl_xor(sum, off);
        rinv[r] = 1.0f / sum;
    }
    // P store (bf16, unnormalized), chunk-swizzled per row
    #pragma unroll
    for (int nc = 0; nc < 16; nc++)
        #pragma unroll
        for (int r = 0; r < 4; r++) {
            int prow = quad * 4 + r;
            int col = nc * 16 + l15;
            int slot = (col >> 3) ^ (prow & 7);
            P[w * 4096 + prow * 256 + slot * 8 + (col & 7)] = f2bf(sc[nc][r]);
        }
    __syncthreads();  // all waves done reading K + writing P

    // scatter V^T[64 d][256 s] from registers, chunk-swizzled:
    // row d, chunk c at slot c^(d&7)
    {
        int chunkc = t >> 3, bytec = t & 7;
        #pragma unroll
        for (int dj = 0; dj < 8; dj++) {
            const u16* xs = (const u16*)&vreg[dj];
            #pragma unroll
            for (int i = 0; i < 8; i++) {
                int vrow = dj * 8 + i;
                kvs[vrow * 256 + ((chunkc ^ (vrow & 7)) * 8) + bytec] = xs[i];
            }
        }
    }
    __syncthreads();

    // phase 2: O = P @ V   (wave: 16 x 64)
    f32x4 accO[4];
    f32x4 zero = {0.f, 0.f, 0.f, 0.f};
    #pragma unroll
    for (int nt = 0; nt < 4; nt++) accO[nt] = zero;
    for (int ks = 0; ks < 8; ks++) {
        int ch = ks * 4 + quad;
        bf16x8 aP = *(const bf16x8*)&P[w * 4096 + l15 * 256 + ((ch ^ (l15 & 7)) * 8)];
        #pragma unroll
        for (int nt = 0; nt < 4; nt++) {
            int vrow = nt * 16 + l15;
            bf16x8 bV = *(const bf16x8*)&kvs[vrow * 256 + ((ch ^ (vrow & 7)) * 8)];
            accO[nt] = __builtin_amdgcn_mfma_f32_16x16x32_bf16(aP, bV, accO[nt], 0, 0, 0);
        }
    }
    // O through LDS (reuse P) -> coalesced 16B stores, 128B row segments
    __syncthreads();
    u16* Ot = P;     // 64 x 64 u16
    #pragma unroll
    for (int nt = 0; nt < 4; nt++)
        #pragma unroll
        for (int r = 0; r < 4; r++) {
            int row = w * 16 + quad * 4 + r;
            int col = nt * 16 + l15;
            int cc = col >> 3;
            Ot[row * 64 + (((cc ^ (row & 7)) * 8) | (col & 7))] =
                f2bf(accO[nt][r] * rinv[r]);
        }
    __syncthreads();
    #pragma unroll
    for (int i = 0; i < 2; i++) {
        int ch = t + i * 256;
        int row = ch >> 3, cc = ch & 7;
        uint4 vv = *(const uint4*)&Ot[row * 64 + ((cc ^ (row & 7)) * 8)];
        *(uint4*)(o + (rowb + qc * 64 + row) * D_ + h * HD_ + cc * 8) = vv;
    }
}

// ---------------------------------------------------------------------------
// LayerNorm: out = LN(in [+ in2] [+ res]) * g + b, optional GELU / PE.
// Vectorized: 4 elems/thread (8-16 B/lane), T = WIDTH/4 threads per row,
// R = 256/T rows per block. INK: 0 = fp32 inputs, 1 = fp16 inputs.
// ---------------------------------------------------------------------------
template <int WIDTH, int INK, bool RES, bool GELU, bool PE, bool SUM2>
__global__ __launch_bounds__(256) void ln_kernel(
    const void* __restrict__ in, const void* __restrict__ in2,
    const u16* __restrict__ res,
    const float* __restrict__ g, const float* __restrict__ b,
    u16* __restrict__ out)
{
    constexpr int T = WIDTH / 4;     // threads per row (32 / 64 / 128)
    constexpr int R = 256 / T;       // rows per block
    __shared__ float rs[R][2], rq[R][2];   // only used when T == 128
    int t = threadIdx.x;
    int r = t / T, j = t % T;
    int row = blockIdx.x * R + r;
    size_t base = (size_t)row * WIDTH + j * 4;
    float v[4];
    if (INK == 0) {
        float4 x = *(const float4*)((const float*)in + base);
        v[0] = x.x; v[1] = x.y; v[2] = x.z; v[3] = x.w;
    } else {
        uint2 x = *(const uint2*)((const u16*)in + base);
        const u16* xs = (const u16*)&x;
        #pragma unroll
        for (int i = 0; i < 4; i++) v[i] = h2f(xs[i]);
    }
    if (SUM2) {
        if (INK == 0) {
            float4 x = *(const float4*)((const float*)in2 + base);
            v[0] += x.x; v[1] += x.y; v[2] += x.z; v[3] += x.w;
        } else {
            uint2 x = *(const uint2*)((const u16*)in2 + base);
            const u16* xs = (const u16*)&x;
            #pragma unroll
            for (int i = 0; i < 4; i++) v[i] += h2f(xs[i]);
        }
    }
    if (RES) {
        uint2 x = *(const uint2*)(res + base);
        const u16* xs = (const u16*)&x;
        #pragma unroll
        for (int i = 0; i < 4; i++) v[i] += bf2f(xs[i]);
    }
    float sm = v[0] + v[1] + v[2] + v[3];
    float sq = v[0] * v[0] + v[1] * v[1] + v[2] * v[2] + v[3] * v[3];
    if constexpr (T >= 64) {
        #pragma unroll
        for (int off = 32; off; off >>= 1) {
            sm += __shfl_xor(sm, off);
            sq += __shfl_xor(sq, off);
        }
    } else {  // T == 32: two rows per wave, confine shuffles to 32 lanes
        #pragma unroll
        for (int off = 16; off; off >>= 1) {
            sm += __shfl_xor(sm, off, 32);
            sq += __shfl_xor(sq, off, 32);
        }
    }
    if constexpr (T == 128) {
        if ((t & 63) == 0) { rs[r][(t >> 6) & 1] = sm; rq[r][(t >> 6) & 1] = sq; }
        __syncthreads();
        sm = rs[r][0] + rs[r][1];
        sq = rq[r][0] + rq[r][1];
    }
    float mean = sm / (float)WIDTH;
    float var = sq / (float)WIDTH - mean * mean;
    float rstd = rsqrtf(var + 1e-5f);
    float4 gv = *(const float4*)(g + j * 4);
    float4 bv = *(const float4*)(b + j * 4);
    const float gs[4] = {gv.x, gv.y, gv.z, gv.w};
    const float bs[4] = {bv.x, bv.y, bv.z, bv.w};
    u16 o4[4];
    #pragma unroll
    for (int i = 0; i < 4; i++) {
        float y = (v[i] - mean) * rstd * gs[i] + bs[i];
        if (GELU) y = gelu_f(y);
        if (PE) {
            const float c = -9.210340371976184f / (float)D_;  // -ln(10000)/D
            int s = row & (S_ - 1);
            int col = j * 4 + i;
            int i2 = col >> 1;
            float ang = (float)s * __expf((float)(2 * i2) * c);
            y += (col & 1) ? __cosf(ang) : __sinf(ang);
        }
        o4[i] = f2bf(y);
    }
    uint2 ov;
    ov.x = (u32)o4[0] | ((u32)o4[1] << 16);
    ov.y = (u32)o4[2] | ((u32)o4[3] << 16);
    *(uint2*)(out + base) = ov;
}

// ---------------------------------------------------------------------------
// Head: out = tanh(y2 @ Wp3 + bp3) * scale + bias. 8 rows x 32 cols per block.
// ---------------------------------------------------------------------------
__global__ __launch_bounds__(256) void head_kernel(
    const u16* __restrict__ y2, const float* __restrict__ W,
    const float* __restrict__ bias, const float* __restrict__ scl,
    const float* __restrict__ bs, float* __restrict__ out)
{
    __shared__ float Ws[128 * ACT_];
    __shared__ u16 Ys[8 * 128];
    int t = threadIdx.x;
    for (int i = t; i < 128 * ACT_; i += 256) Ws[i] = W[i];
    int r0 = blockIdx.x * 8;
    for (int i = t; i < 8 * 128; i += 256) Ys[i] = y2[(size_t)r0 * 128 + i];
    __syncthreads();
    int lr = t >> 5, c = t & 31;
    if (c < ACT_) {
        float acc = bias[c];
        for (int kk = 0; kk < 128; kk++)
            acc += bf2f(Ys[lr * 128 + kk]) * Ws[kk * ACT_ + c];
        float y = tanhf(acc);
        out[(size_t)(r0 + lr) * ACT_ + c] = y * scl[c] + bs[c];
    }
}

// ---------------------------------------------------------------------------
extern "C" void kernel_launch(void* const* d_in, const int* in_sizes, int n_in,
                              void* d_out, int out_size, void* d_ws, size_t ws_size,
                              hipStream_t stream)
{
    const float* obs   = (const float*)d_in[0];
    const float* W_in  = (const float*)d_in[1];
    const float* b_in  = (const float*)d_in[2];
    const float* g_in  = (const float*)d_in[3];
    const float* be_in = (const float*)d_in[4];
    const float* Wq  = (const float*)d_in[5];
    const float* bq  = (const float*)d_in[6];
    const float* Wk  = (const float*)d_in[7];
    const float* bk  = (const float*)d_in[8];
    const float* Wv  = (const float*)d_in[9];
    const float* bv  = (const float*)d_in[10];
    const float* Wo  = (const float*)d_in[11];
    const float* bo  = (const float*)d_in[12];
    const float* g1  = (const float*)d_in[13];
    const float* be1 = (const float*)d_in[14];
    const float* W1  = (const float*)d_in[15];
    const float* b1  = (const float*)d_in[16];
    const float* W2  = (const float*)d_in[17];
    const float* b2  = (const float*)d_in[18];
    const float* g2  = (const float*)d_in[19];
    const float* be2 = (const float*)d_in[20];
    const float* Wp1  = (const float*)d_in[21];
    const float* bp1  = (const float*)d_in[22];
    const float* gp1  = (const float*)d_in[23];
    const float* bep1 = (const float*)d_in[24];
    const float* Wp2  = (const float*)d_in[25];
    const float* bp2  = (const float*)d_in[26];
    const float* gp2  = (const float*)d_in[27];
    const float* bep2 = (const float*)d_in[28];
    const float* Wp3  = (const float*)d_in[29];
    const float* bp3  = (const float*)d_in[30];
    const float* ascl = (const float*)d_in[31];
    const float* abias = (const float*)d_in[32];

    char* ws = (char*)d_ws;
    size_t off = 0;
    auto alloc = [&](size_t bytes) {
        void* p = ws + off;
        off += (bytes + 255) & ~(size_t)255;
        return p;
    };
    u16* WQKVT = (u16*)alloc((size_t)L_ * QKV3 * D_ * 2);     // 12.6 MB
    u16* WOT   = (u16*)alloc((size_t)L_ * D_ * D_ * 2);       // 4 MB
    u16* W1T   = (u16*)alloc((size_t)L_ * D_ * FF_ * 2);      // 16 MB
    u16* W2T   = (u16*)alloc((size_t)L_ * FF_ * D_ * 2);      // 16 MB
    u16* WP1T  = (u16*)alloc((size_t)D_ * (D_ / 2) * 2);
    u16* WP2T  = (u16*)alloc((size_t)(D_ / 2) * (D_ / 4) * 2);
    float* bqkv = (float*)alloc((size_t)L_ * QKV3 * 4);
    u16* x_bf = (u16*)alloc((size_t)NTOK * D_ * 2);           // 16 MB
    float* tmp = (float*)alloc((size_t)NTOK * D_ * 4);        // 32 MB (f32 or f16 use)
    char* regionA = (char*)alloc((size_t)NTOK * FF_ * 2);     // 64 MB
    size_t base_need = off;
    char* tmp2 = ws + base_need;                              // +16 MB if fits
    bool split = (ws_size >= base_need + (size_t)NTOK * D_ * 2);
    (void)in_sizes; (void)n_in; (void)out_size;

    u16* qkvbuf = (u16*)(regionA);                            // 48 MB
    u16* obuf = (u16*)(regionA + (size_t)NTOK * QKV3 * 2);    // 16 MB
    u16* hbuf = (u16*)(regionA);                              // 64 MB (aliases)
    // head-phase aliases (regionA free then)
    u16* y1_bf = (u16*)(regionA);                             // 8 MB
    u16* y2_bf = (u16*)(regionA + (32u << 20));               // 4 MB

    dim3 tb(32, 8);
    size_t DD = (size_t)D_ * D_;
    transpose_bf16_kernel<<<dim3(16, 16, L_), tb, 0, stream>>>(
        Wq, WQKVT, D_, D_, DD, (size_t)QKV3 * D_);
    transpose_bf16_kernel<<<dim3(16, 16, L_), tb, 0, stream>>>(
        Wk, WQKVT + DD, D_, D_, DD, (size_t)QKV3 * D_);
    transpose_bf16_kernel<<<dim3(16, 16, L_), tb, 0, stream>>>(
        Wv, WQKVT + 2 * DD, D_, D_, DD, (size_t)QKV3 * D_);
    transpose_bf16_kernel<<<dim3(16, 16, L_), tb, 0, stream>>>(
        Wo, WOT, D_, D_, DD, DD);
    transpose_bf16_kernel<<<dim3(64, 16, L_), tb, 0, stream>>>(
        W1, W1T, D_, FF_, (size_t)D_ * FF_, (size_t)D_ * FF_);
    transpose_bf16_kernel<<<dim3(16, 64, L_), tb, 0, stream>>>(
        W2, W2T, FF_, D_, (size_t)D_ * FF_, (size_t)D_ * FF_);
    transpose_bf16_kernel<<<dim3(8, 16, 1), tb, 0, stream>>>(
        Wp1, WP1T, D_, D_ / 2, 0, 0);
    transpose_bf16_kernel<<<dim3(4, 8, 1), tb, 0, stream>>>(
        Wp2, WP2T, D_ / 2, D_ / 4, 0, 0);
    concat_bias_kernel<<<L_ * QKV3 / 256, 256, 0, stream>>>(bq, bk, bv, bqkv);

    in_gemm_kernel<<<dim3(D_ / 64, NTOK / 64), 256, 0, stream>>>(
        obs, W_in, b_in, tmp);
    ln_kernel<D_, 0, false, true, true, false><<<NTOK / 2, 256, 0, stream>>>(
        tmp, nullptr, nullptr, g_in, be_in, x_bf);

    const int MG = NTOK / 128;  // 128 M-blocks; grid = 128 * NX (y-fast)
    for (int l = 0; l < L_; l++) {
        const u16* wqkvt = WQKVT + (size_t)l * QKV3 * D_;
        const u16* wot = WOT + (size_t)l * DD;
        const u16* w1t = W1T + (size_t)l * D_ * FF_;
        const u16* w2t = W2T + (size_t)l * FF_ * D_;

        gemm_bt_kernel<0, 128, false><<<MG * (QKV3 / 128), 256, 0, stream>>>(
            x_bf, wqkvt, bqkv + l * QKV3, qkvbuf, nullptr, NTOK, QKV3, D_, D_);
        attn_kernel<<<B_ * H_ * (S_ / 64), 256, 0, stream>>>(qkvbuf, obuf);
        if (split) {
            gemm_bt_kernel<3, 128, true><<<dim3(MG * 4, 1, 2), 256, 0, stream>>>(
                obuf, wot, bo + l * D_, tmp, tmp2, NTOK, D_, D_, D_ / 2);
            ln_kernel<D_, 1, true, false, false, true><<<NTOK / 2, 256, 0, stream>>>(
                tmp, tmp2, x_bf, g1 + l * D_, be1 + l * D_, x_bf);
        } else {
            gemm_bt_kernel<2, 128, false><<<MG * 4, 256, 0, stream>>>(
                obuf, wot, bo + l * D_, tmp, nullptr, NTOK, D_, D_, D_);
            ln_kernel<D_, 0, true, false, false, false><<<NTOK / 2, 256, 0, stream>>>(
                tmp, nullptr, x_bf, g1 + l * D_, be1 + l * D_, x_bf);
        }
        gemm_bt_kernel<1, 128, false><<<MG * (FF_ / 128), 256, 0, stream>>>(
            x_bf, w1t, b1 + l * FF_, hbuf, nullptr, NTOK, FF_, D_, D_);
        if (split) {
            gemm_bt_kernel<3, 128, true><<<dim3(MG * 4, 1, 2), 256, 0, stream>>>(
                hbuf, w2t, b2 + l * D_, tmp, tmp2, NTOK, D_, FF_, FF_ / 2);
            ln_kernel<D_, 1, true, false, false, true><<<NTOK / 2, 256, 0, stream>>>(
                tmp, tmp2, x_bf, g2 + l * D_, be2 + l * D_, x_bf);
        } else {
            gemm_bt_kernel<2, 128, false><<<MG * 4, 256, 0, stream>>>(
                hbuf, w2t, b2 + l * D_, tmp, nullptr, NTOK, D_, FF_, FF_);
            ln_kernel<D_, 0, true, false, false, false><<<NTOK / 2, 256, 0, stream>>>(
                tmp, nullptr, x_bf, g2 + l * D_, be2 + l * D_, x_bf);
        }
    }

    // policy head
    if (split) {
        gemm_bt_kernel<3, 64, true><<<dim3(MG * 4, 1, 2), 256, 0, stream>>>(
            x_bf, WP1T, bp1, tmp, tmp2, NTOK, D_ / 2, D_, D_ / 2);
        ln_kernel<D_ / 2, 1, false, true, false, true><<<NTOK / 4, 256, 0, stream>>>(
            tmp, tmp2, nullptr, gp1, bep1, y1_bf);
        gemm_bt_kernel<3, 64, true><<<dim3(MG * 2, 1, 2), 256, 0, stream>>>(
            y1_bf, WP2T, bp2, tmp, tmp2, NTOK, D_ / 4, D_ / 2, D_ / 4);
        ln_kernel<D_ / 4, 1, false, true, false, true><<<NTOK / 8, 256, 0, stream>>>(
            tmp, tmp2, nullptr, gp2, bep2, y2_bf);
    } else {
        gemm_bt_kernel<2, 64, false><<<MG * 4, 256, 0, stream>>>(
            x_bf, WP1T, bp1, tmp, nullptr, NTOK, D_ / 2, D_, D_);
        ln_kernel<D_ / 2, 0, false, true, false, false><<<NTOK / 4, 256, 0, stream>>>(
            tmp, nullptr, nullptr, gp1, bep1, y1_bf);
        gemm_bt_kernel<2, 64, false><<<MG * 2, 256, 0, stream>>>(
            y1_bf, WP2T, bp2, tmp, nullptr, NTOK, D_ / 4, D_ / 2, D_ / 2);
        ln_kernel<D_ / 4, 0, false, true, false, false><<<NTOK / 8, 256, 0, stream>>>(
            tmp, nullptr, nullptr, gp2, bep2, y2_bf);
    }
    head_kernel<<<NTOK / 8, 256, 0, stream>>>(
        y2_bf, Wp3, bp3, ascl, abias, (float*)d_out);
}